// Round 12
// baseline (813.387 us; speedup 1.0000x reference)
//
#include <hip/hip_runtime.h>

#define D_FEAT 4096
#define HID 50
#define NC 6
#define BCAP 10240   // records per bucket region (avg ~8184)
#define CSTRIDE 16   // cursor padding: 1 counter per 64B cache line
#define ZS 8         // padded z-row stride (floats)
#define BK 32        // K-floats per staged A-chunk

typedef __attribute__((ext_vector_type(8))) short bf16x8;
typedef __attribute__((ext_vector_type(4))) float f32x4;

// ============ W1 -> bf16 hi/lo MFMA B-fragment pre-pack ============
__global__ __launch_bounds__(256) void prep_wfrag(
    const float* __restrict__ W1, ushort* __restrict__ Whi,
    ushort* __restrict__ Wlo)
{
    int idx = blockIdx.x * 256 + threadIdx.x;   // 0 .. 128*4*64*8-1
    int j  = idx & 7;
    int l  = (idx >> 3) & 63;
    int ct = (idx >> 9) & 3;
    int kc = idx >> 11;
    int k = kc * 32 + (l >> 4) * 8 + j;
    int c = ct * 16 + (l & 15);
    float v = (c < HID) ? W1[k * HID + c] : 0.f;
    unsigned b = __float_as_uint(v);
    unsigned h = (b + 0x8000u) >> 16;                 // round-half-up bf16
    float hf = __uint_as_float(h << 16);
    float lr = v - hf;
    unsigned lo = (__float_as_uint(lr) + 0x8000u) >> 16;
    Whi[idx] = (ushort)h;
    Wlo[idx] = (ushort)lo;
}

// ---- A fp32 -> bf16 hi(trunc)/lo(trunc residual), v_perm packed ----
__device__ __forceinline__ void split_a(const f32x4 a0, const f32x4 a1,
                                        bf16x8& hi, bf16x8& lo)
{
    union U4 { unsigned u[4]; bf16x8 v; } hw, lw;
#pragma unroll
    for (int p = 0; p < 4; ++p) {
        float v0 = (p < 2) ? a0[2 * p]     : a1[2 * p - 4];
        float v1 = (p < 2) ? a0[2 * p + 1] : a1[2 * p - 3];
        unsigned b0 = __float_as_uint(v0), b1 = __float_as_uint(v1);
        hw.u[p] = __builtin_amdgcn_perm(b1, b0, 0x07060302u);
        float l0f = v0 - __uint_as_float(b0 & 0xFFFF0000u);
        float l1f = v1 - __uint_as_float(b1 & 0xFFFF0000u);
        lw.u[p] = __builtin_amdgcn_perm(__float_as_uint(l1f),
                                        __float_as_uint(l0f), 0x07060302u);
    }
    hi = hw.v; lo = lw.v;
}

// ============ MEGA1: gemm blocks [0,ngemm) + scatter blocks [ngemm,..) ====
// GEMM: WAVE-PRIVATE staging — each wave owns 32 rows and a private 12KB
// LDS region (3 x 4KB chunk buffers). No barriers. Depth-3 glds prefetch
// with exact counted vmcnt (in-order retirement makes vmcnt(N) a hard
// guarantee). Per iter: 4 glds + 8 B-loads, order pinned by sched_barrier.
__global__ __launch_bounds__(256, 3) void mega1(
    const float* __restrict__ F, const ushort* __restrict__ Whi,
    const ushort* __restrict__ Wlo, const float* __restrict__ b1,
    float* __restrict__ H, int nrows, int ngemm,
    const int* __restrict__ sx, const int* __restrict__ sy,
    const float* __restrict__ rel, int* __restrict__ cursor,
    uint2* __restrict__ pool, int m, int nbuck)
{
    __shared__ union {
        float abuf[4][3][1024];                 // 48 KB: 4 waves x 3 bufs x 4KB
        struct { int hist[1024]; int gb[1024]; } sc;
    } u;

    if ((int)blockIdx.x < ngemm) {
        // ---------------- GEMM tile (128 rows x 64 cols) ----------------
        const int tid = threadIdx.x;
        const int w  = tid >> 6;
        const int l  = tid & 63;
        const int l16 = l & 15, lq = l >> 4;
        const long rowb = (long)blockIdx.x * 128 + (long)w * 32;
        char* abase = (char*)u.abuf + w * 12288;   // wave-private 12KB

        // per-lane pre-swizzled global sources: lane i of glds inst p covers
        // LDS (row = p*8 + i/8, physbyte = (i&7)*16); logical col =
        // physbyte ^ ((row&7)<<4), row&7 == i>>3.
        const int swzf = ((((l & 7) * 16) ^ ((l >> 3) << 4)) >> 2);
        const float* gsrc[4];
#pragma unroll
        for (int p = 0; p < 4; ++p) {
            long rr = rowb + p * 8 + (l >> 3);
            if (rr > (long)nrows - 1) rr = (long)nrows - 1;
            gsrc[p] = F + rr * (long)D_FEAT + swzf;
        }

        // swizzled ds_read offsets within the wave's buf
        const int rdoff0 = l16 * 128 + ((lq * 32) ^ ((l16 & 7) << 4));
        const int rdoff1 = (l16 + 16) * 128 + ((lq * 32) ^ ((l16 & 7) << 4));

        const bf16x8* bhip = (const bf16x8*)Whi + l;   // + kc*256 + ct*64
        const bf16x8* blop = (const bf16x8*)Wlo + l;

        f32x4 acc[2][4];
#pragma unroll
        for (int rt = 0; rt < 2; ++rt)
#pragma unroll
            for (int ct = 0; ct < 4; ++ct)
#pragma unroll
                for (int i = 0; i < 4; ++i) acc[rt][ct][i] = 0.f;

        bf16x8 bh[2][4], bl[2][4];

#define GSTAGE(BUF, KS)                                                       \
        _Pragma("unroll")                                                     \
        for (int p = 0; p < 4; ++p)                                           \
            __builtin_amdgcn_global_load_lds(                                 \
                (const __attribute__((address_space(1))) void*)(gsrc[p] + (long)(KS) * BK), \
                (__attribute__((address_space(3))) void*)(abase + (BUF) * 4096 + p * 1024), \
                16, 0, 0);

        // prologue: stage chunks 0,1,2 (order pinned), then B(0)
        GSTAGE(0, 0)
        __builtin_amdgcn_sched_barrier(0);
        GSTAGE(1, 1)
        __builtin_amdgcn_sched_barrier(0);
        GSTAGE(2, 2)
        __builtin_amdgcn_sched_barrier(0);
#pragma unroll
        for (int ct = 0; ct < 4; ++ct) { bh[0][ct] = bhip[ct * 64]; bl[0][ct] = blop[ct * 64]; }

// ITER: consume chunk KC from buf BUF(=KC%3) with B-set BC(=KC&1);
// prefetch B(KC+1)->BN, stage chunk KC+3 into BUF. VC = exact vmcnt count.
#define ITER(KC, BUF, BC, BN, VC)                                             \
        {                                                                     \
            asm volatile("s_waitcnt vmcnt(" #VC ")" ::: "memory");            \
            __builtin_amdgcn_sched_barrier(0);                                \
            const char* rb_ = abase + (BUF) * 4096;                           \
            f32x4 a00 = *(const f32x4*)(rb_ + rdoff0);                        \
            f32x4 a01 = *(const f32x4*)(rb_ + (rdoff0 ^ 16));                 \
            f32x4 a10 = *(const f32x4*)(rb_ + rdoff1);                        \
            f32x4 a11 = *(const f32x4*)(rb_ + (rdoff1 ^ 16));                 \
            asm volatile("s_waitcnt lgkmcnt(0)" ::: "memory");                \
            __builtin_amdgcn_sched_barrier(0);                                \
            const int ks_ = ((KC) + 3 <= 127) ? (KC) + 3 : 127;               \
            GSTAGE(BUF, ks_)                                                  \
            __builtin_amdgcn_sched_barrier(0);                                \
            const int kb_ = ((KC) + 1 <= 127) ? (KC) + 1 : 127;               \
            _Pragma("unroll")                                                 \
            for (int ct = 0; ct < 4; ++ct) {                                  \
                bh[BN][ct] = bhip[kb_ * 256 + ct * 64];                       \
                bl[BN][ct] = blop[kb_ * 256 + ct * 64];                       \
            }                                                                 \
            bf16x8 ahi0, alo0, ahi1, alo1;                                    \
            split_a(a00, a01, ahi0, alo0);                                    \
            split_a(a10, a11, ahi1, alo1);                                    \
            _Pragma("unroll")                                                 \
            for (int ct = 0; ct < 4; ++ct) {                                  \
                acc[0][ct] = __builtin_amdgcn_mfma_f32_16x16x32_bf16(ahi0, bh[BC][ct], acc[0][ct], 0, 0, 0); \
                acc[0][ct] = __builtin_amdgcn_mfma_f32_16x16x32_bf16(ahi0, bl[BC][ct], acc[0][ct], 0, 0, 0); \
                acc[0][ct] = __builtin_amdgcn_mfma_f32_16x16x32_bf16(alo0, bh[BC][ct], acc[0][ct], 0, 0, 0); \
                acc[1][ct] = __builtin_amdgcn_mfma_f32_16x16x32_bf16(ahi1, bh[BC][ct], acc[1][ct], 0, 0, 0); \
                acc[1][ct] = __builtin_amdgcn_mfma_f32_16x16x32_bf16(ahi1, bl[BC][ct], acc[1][ct], 0, 0, 0); \
                acc[1][ct] = __builtin_amdgcn_mfma_f32_16x16x32_bf16(alo1, bh[BC][ct], acc[1][ct], 0, 0, 0); \
            }                                                                 \
        }

        // peeled prologue iters (exact counts: 16, 24, then steady 32)
        ITER(0, 0, 0, 1, 16)
        ITER(1, 1, 1, 0, 24)
        ITER(2, 2, 0, 1, 32)

        // main loop: period-6 (3 bufs x 2 B-sets); kk = 3,9,...,117 (odd)
#pragma unroll 1
        for (int kk = 3; kk <= 117; kk += 6) {
            ITER(kk + 0, 0, 1, 0, 32)
            ITER(kk + 1, 1, 0, 1, 32)
            ITER(kk + 2, 2, 1, 0, 32)
            ITER(kk + 3, 0, 0, 1, 32)
            ITER(kk + 4, 1, 1, 0, 32)
            ITER(kk + 5, 2, 0, 1, 32)
        }
        // tail: 123..127
        ITER(123, 0, 1, 0, 32)
        ITER(124, 1, 0, 1, 32)
        ITER(125, 2, 1, 0, 32)
        ITER(126, 0, 0, 1, 32)
        ITER(127, 1, 1, 0, 32)
#undef ITER
#undef GSTAGE

        // epilogue: D row = (lane>>4)*4 + i, col = ct*16 + (lane&15)
#pragma unroll
        for (int ct = 0; ct < 4; ++ct) {
            int col = ct * 16 + l16;
            if (col >= HID) continue;
            float bias = b1[col];
#pragma unroll
            for (int rt = 0; rt < 2; ++rt)
#pragma unroll
                for (int i = 0; i < 4; ++i) {
                    long row = rowb + rt * 16 + lq * 4 + i;
                    if (row < nrows) {
                        float v = acc[rt][ct][i] + bias;
                        H[row * HID + col] = v > 0.f ? v : 0.f;
                    }
                }
        }
    } else {
        // ------------- scatter-bucket tile (4096 edges, rank-only regs) ----
        const int bid = blockIdx.x - ngemm;
        const int t = threadIdx.x;
        for (int i = t; i < 1024; i += 256) u.sc.hist[i] = 0;
        __syncthreads();

        const int e0 = bid * 4096;
        unsigned prA[16], prB[16];
#pragma unroll
        for (int k = 0; k < 16; ++k) {
            int e = e0 + k * 256 + t;
            if (e < m) {
                int x = sx[e], y = sy[e];
                int bA = x >> 7;
                prA[k] = ((unsigned)bA << 22) | (unsigned)atomicAdd(&u.sc.hist[bA], 1);
                int bB = y >> 7;
                prB[k] = ((unsigned)bB << 22) | (unsigned)atomicAdd(&u.sc.hist[bB], 1);
            } else {
                prA[k] = 0xFFFFFFFFu; prB[k] = 0xFFFFFFFFu;
            }
        }
        __syncthreads();
        for (int b = t; b < nbuck; b += 256) {
            int h = u.sc.hist[b];
            u.sc.gb[b] = h ? atomicAdd(&cursor[b * CSTRIDE], h) : 0;
        }
        __syncthreads();
#pragma unroll
        for (int k = 0; k < 16; ++k) {
            if (prA[k] == 0xFFFFFFFFu) continue;
            int e = e0 + k * 256 + t;
            int x = sx[e], y = sy[e];               // L2-hot re-read
            unsigned rb = __float_as_uint(rel[e]);
            {
                unsigned buck = prA[k] >> 22, rank = prA[k] & 0x3FFFFFu;
                unsigned slot = (unsigned)u.sc.gb[buck] + rank;
                if (slot < BCAP)
                    pool[(size_t)buck * BCAP + slot] =
                        make_uint2((unsigned)(x & 127) | ((unsigned)y << 8), rb);
            }
            {
                unsigned buck = prB[k] >> 22, rank = prB[k] & 0x3FFFFFu;
                unsigned slot = (unsigned)u.sc.gb[buck] + rank;
                if (slot < BCAP)
                    pool[(size_t)buck * BCAP + slot] =
                        make_uint2((unsigned)(y & 127) | 0x80u | ((unsigned)x << 8), rb);
            }
        }
    }
}

// exclusive scan of clamped bucket counts (nb <= 1024)
__global__ __launch_bounds__(1024) void scan_buckets(
    const int* __restrict__ cursor, int* __restrict__ bucket_base, int nb)
{
    __shared__ int s[1024];
    int t = threadIdx.x;
    int v = 0;
    if (t < nb) { v = cursor[t * CSTRIDE]; if (v > BCAP) v = BCAP; }
    s[t] = v;
    __syncthreads();
    for (int st = 1; st < 1024; st <<= 1) {
        int tmp = (t >= st) ? s[t - st] : 0;
        __syncthreads();
        s[t] += tmp;
        __syncthreads();
    }
    if (t < nb) bucket_base[t] = s[t] - v;
}

// ============ MEGA2: mlp blocks [0,nmlp) + sort blocks [nmlp,..) ============
__global__ __launch_bounds__(256) void mega2(
    const float* __restrict__ H,
    const float* __restrict__ W2, const float* __restrict__ b2,
    const float* __restrict__ W3, const float* __restrict__ b3,
    const float* __restrict__ Wl, const float* __restrict__ bl,
    float* __restrict__ Z, int n, int nmlp, int zs,
    const uint2* __restrict__ pool, const int* __restrict__ cursor,
    const int* __restrict__ bucket_base, uint2* __restrict__ recs,
    int* __restrict__ offs, int* __restrict__ deg)
{
    __shared__ union {
        struct {
            float w2[HID][52];
            float w3[HID][52];
            float wl[52][8];
            float bb2[52], bb3[52], bbl[8];
        } mlp;
        struct {
            int hist[128], nbase[128], cur[128], sc[128];
            ushort ord[BCAP];
        } srt;
    } u;

    if ((int)blockIdx.x < nmlp) {
        // ---------------- MLP tail ----------------
        for (int i = threadIdx.x; i < HID * 52; i += 256) {
            int r = i / 52, c = i % 52;
            u.mlp.w2[r][c] = (c < HID) ? W2[r * HID + c] : 0.f;
            u.mlp.w3[r][c] = (c < HID) ? W3[r * HID + c] : 0.f;
        }
        for (int i = threadIdx.x; i < 52 * 8; i += 256) {
            int r = i / 8, c = i % 8;
            u.mlp.wl[r][c] = (r < HID && c < NC) ? Wl[r * NC + c] : 0.f;
        }
        if (threadIdx.x < 52) {
            u.mlp.bb2[threadIdx.x] = (threadIdx.x < HID) ? b2[threadIdx.x] : 0.f;
            u.mlp.bb3[threadIdx.x] = (threadIdx.x < HID) ? b3[threadIdx.x] : 0.f;
        }
        if (threadIdx.x < 8) u.mlp.bbl[threadIdx.x] = (threadIdx.x < NC) ? bl[threadIdx.x] : 0.f;
        __syncthreads();

        long row = (long)blockIdx.x * 256 + threadIdx.x;
        if (row >= n) return;

        float x1[HID];
#pragma unroll
        for (int i = 0; i < HID / 2; ++i) {
            float2 t = *(const float2*)(H + row * HID + 2 * i);
            x1[2 * i] = t.x; x1[2 * i + 1] = t.y;
        }

        float x2[52];
#pragma unroll
        for (int j = 0; j < 52; ++j) x2[j] = u.mlp.bb2[j];
        for (int i = 0; i < HID; ++i) {
            float xi = x1[i];
#pragma unroll
            for (int jq = 0; jq < 13; ++jq) {
                float4 t = *(const float4*)&u.mlp.w2[i][jq * 4];
                x2[jq * 4 + 0] = fmaf(xi, t.x, x2[jq * 4 + 0]);
                x2[jq * 4 + 1] = fmaf(xi, t.y, x2[jq * 4 + 1]);
                x2[jq * 4 + 2] = fmaf(xi, t.z, x2[jq * 4 + 2]);
                x2[jq * 4 + 3] = fmaf(xi, t.w, x2[jq * 4 + 3]);
            }
        }
#pragma unroll
        for (int j = 0; j < 52; ++j) x2[j] = fmaxf(x2[j], 0.f);

        float z[NC];
#pragma unroll
        for (int c = 0; c < NC; ++c) z[c] = u.mlp.bbl[c];
        for (int jq = 0; jq < 13; ++jq) {
            float t0 = u.mlp.bb3[jq * 4 + 0], t1 = u.mlp.bb3[jq * 4 + 1];
            float t2 = u.mlp.bb3[jq * 4 + 2], t3 = u.mlp.bb3[jq * 4 + 3];
            for (int k = 0; k < HID; ++k) {
                float xk = x2[k];
                float4 wv = *(const float4*)&u.mlp.w3[k][jq * 4];
                t0 = fmaf(xk, wv.x, t0);
                t1 = fmaf(xk, wv.y, t1);
                t2 = fmaf(xk, wv.z, t2);
                t3 = fmaf(xk, wv.w, t3);
            }
            t0 = fmaxf(t0, 0.f); t1 = fmaxf(t1, 0.f);
            t2 = fmaxf(t2, 0.f); t3 = fmaxf(t3, 0.f);
#pragma unroll
            for (int c = 0; c < NC; ++c) {
                z[c] = fmaf(t0, u.mlp.wl[jq * 4 + 0][c], z[c]);
                z[c] = fmaf(t1, u.mlp.wl[jq * 4 + 1][c], z[c]);
                z[c] = fmaf(t2, u.mlp.wl[jq * 4 + 2][c], z[c]);
                z[c] = fmaf(t3, u.mlp.wl[jq * 4 + 3][c], z[c]);
            }
        }
        if (zs == ZS) {
            float* po = Z + (size_t)ZS * row;
            *(float4*)po       = make_float4(z[0], z[1], z[2], z[3]);
            *(float4*)(po + 4) = make_float4(z[4], z[5], 0.f, 0.f);
        } else {
#pragma unroll
            for (int c = 0; c < NC; ++c) Z[row * NC + c] = z[c];
        }
    } else {
        // ---------------- per-bucket counting sort ----------------
        const int b = blockIdx.x - nmlp;
        const int t = threadIdx.x;
        int cnt = cursor[b * CSTRIDE]; if (cnt > BCAP) cnt = BCAP;
        const int base = bucket_base[b];
        if (t < 128) u.srt.hist[t] = 0;
        __syncthreads();
        const uint2* bp = pool + (size_t)b * BCAP;
        for (int i = t; i < cnt; i += 256)
            atomicAdd(&u.srt.hist[bp[i].x & 127u], 1);
        __syncthreads();
        int v = (t < 128) ? u.srt.hist[t] : 0;
        if (t < 128) u.srt.sc[t] = v;
        __syncthreads();
        for (int st = 1; st < 128; st <<= 1) {
            int tmp = (t >= st && t < 128) ? u.srt.sc[t - st] : 0;
            __syncthreads();
            if (t < 128) u.srt.sc[t] += tmp;
            __syncthreads();
        }
        if (t < 128) {
            u.srt.nbase[t] = u.srt.sc[t] - v;
            u.srt.cur[t] = 0;
            int gnode = b * 128 + t;
            if (gnode < n) { offs[gnode] = base + u.srt.sc[t] - v; deg[gnode] = v; }
        }
        __syncthreads();
        for (int i = t; i < cnt; i += 256) {
            unsigned nl = bp[i].x & 127u;
            int rk = atomicAdd(&u.srt.cur[nl], 1);
            u.srt.ord[u.srt.nbase[nl] + rk] = (ushort)i;
        }
        __syncthreads();
        for (int i = t; i < cnt; i += 256) {
            uint2 r = bp[u.srt.ord[i]];
            unsigned side = (r.x >> 7) & 1u;
            unsigned other = r.x >> 8;
            recs[base + i] = make_uint2(other | (side << 31), r.y);
        }
    }
}

// ============ KENN layer: 8 lanes per node, shfl reduce, padded Z ============
__global__ __launch_bounds__(256) void kenn_gather8(
    const float* __restrict__ Zin, float* __restrict__ Zout,
    const int* __restrict__ offs, const int* __restrict__ deg,
    const uint2* __restrict__ recs, const float* __restrict__ cw,
    int n, int dofinal)
{
    int gt = blockIdx.x * 256 + threadIdx.x;
    int node = gt >> 3;
    int l8 = gt & 7;
    if (node >= n) return;

    float4 za = *(const float4*)(Zin + (size_t)ZS * node);
    float4 zb = *(const float4*)(Zin + (size_t)ZS * node + 4);
    float zown[NC] = { za.x, za.y, za.z, za.w, zb.x, zb.y };
    float acc[NC], cwv[NC];
#pragma unroll
    for (int c = 0; c < NC; ++c) { acc[c] = 0.f; cwv[c] = cw[c]; }

    const int start = offs[node];
    const int cnt = deg[node];

#pragma unroll 2
    for (int i = l8; i < cnt; i += 8) {
        uint2 rc = recs[start + i];
        const int other = (int)(rc.x & 0x7FFFFFFFu);
        const bool sideY = (rc.x & 0x80000000u) != 0;
        const float l0 = -__uint_as_float(rc.y);

        float4 oa = *(const float4*)(Zin + (size_t)ZS * other);
        float4 ob = *(const float4*)(Zin + (size_t)ZS * other + 4);
        float zo[NC] = { oa.x, oa.y, oa.z, oa.w, ob.x, ob.y };

#pragma unroll
        for (int c = 0; c < NC; ++c) {
            float zx = sideY ? zo[c] : zown[c];
            float zy = sideY ? zown[c] : zo[c];
            float l1 = -zx;
            float l2 = zy;
            float mx = fmaxf(l0, fmaxf(l1, l2));
            float e0 = __expf(l0 - mx);
            float e1 = __expf(l1 - mx);
            float e2 = __expf(l2 - mx);
            float g = cwv[c] * __builtin_amdgcn_rcpf(e0 + e1 + e2);
            acc[c] += sideY ? (e2 * g) : (-e1 * g);
        }
    }

#pragma unroll
    for (int c = 0; c < NC; ++c) {
        acc[c] += __shfl_xor(acc[c], 1, 64);
        acc[c] += __shfl_xor(acc[c], 2, 64);
        acc[c] += __shfl_xor(acc[c], 4, 64);
    }

    if (l8 != 0) return;

#pragma unroll
    for (int c = 0; c < NC; ++c) acc[c] += zown[c];

    if (dofinal) {
        float mx = acc[0];
#pragma unroll
        for (int c = 1; c < NC; ++c) mx = fmaxf(mx, acc[c]);
        float e[NC], s = 0.f;
#pragma unroll
        for (int c = 0; c < NC; ++c) { e[c] = __expf(acc[c] - mx); s += e[c]; }
        float inv = 1.f / s;
        float2* po = (float2*)(Zout + 6L * node);   // compact output
#pragma unroll
        for (int q = 0; q < 3; ++q) {
            float2 t; t.x = e[2 * q] * inv; t.y = e[2 * q + 1] * inv;
            po[q] = t;
        }
    } else {
        float* po = Zout + (size_t)ZS * node;
        *(float4*)po       = make_float4(acc[0], acc[1], acc[2], acc[3]);
        *(float4*)(po + 4) = make_float4(acc[4], acc[5], 0.f, 0.f);
    }
}

// ---------------- fallback path kernels (atomic version, compact Z) --------
__global__ __launch_bounds__(256) void kenn_edge(
    const float* __restrict__ Zold, float* __restrict__ Znew,
    const float* __restrict__ rel, const int* __restrict__ sx,
    const int* __restrict__ sy, const float* __restrict__ cw, int m)
{
    int idx = blockIdx.x * 256 + threadIdx.x;
    if (idx >= m) return;
    const int x = sx[idx];
    const int y = sy[idx];
    const float l0 = -rel[idx];

    float zx[NC], zy[NC];
    const float2* px = (const float2*)(Zold + 6L * x);
    const float2* py = (const float2*)(Zold + 6L * y);
#pragma unroll
    for (int q = 0; q < 3; ++q) {
        float2 t = px[q]; zx[2 * q] = t.x; zx[2 * q + 1] = t.y;
        float2 u = py[q]; zy[2 * q] = u.x; zy[2 * q + 1] = u.y;
    }
#pragma unroll
    for (int c = 0; c < NC; ++c) {
        float l1 = -zx[c];
        float l2 = zy[c];
        float mx = fmaxf(l0, fmaxf(l1, l2));
        float e0 = __expf(l0 - mx);
        float e1 = __expf(l1 - mx);
        float e2 = __expf(l2 - mx);
        float s = cw[c] / (e0 + e1 + e2);
        atomicAdd(&Znew[6L * x + c], -e1 * s);
        atomicAdd(&Znew[6L * y + c],  e2 * s);
    }
}

__global__ __launch_bounds__(256) void softmax6(
    const float* __restrict__ Z, float* __restrict__ out, int n)
{
    long row = (long)blockIdx.x * 256 + threadIdx.x;
    if (row >= n) return;
    float v[NC];
    const float2* p = (const float2*)(Z + row * 6);
#pragma unroll
    for (int q = 0; q < 3; ++q) { float2 t = p[q]; v[2 * q] = t.x; v[2 * q + 1] = t.y; }
    float mx = v[0];
#pragma unroll
    for (int c = 1; c < NC; ++c) mx = fmaxf(mx, v[c]);
    float e[NC], s = 0.f;
#pragma unroll
    for (int c = 0; c < NC; ++c) { e[c] = __expf(v[c] - mx); s += e[c]; }
    float inv = 1.f / s;
    float2* po = (float2*)(out + row * 6);
#pragma unroll
    for (int q = 0; q < 3; ++q) {
        float2 t; t.x = e[2 * q] * inv; t.y = e[2 * q + 1] * inv;
        po[q] = t;
    }
}

extern "C" void kernel_launch(void* const* d_in, const int* in_sizes, int n_in,
                              void* d_out, int out_size, void* d_ws, size_t ws_size,
                              hipStream_t stream)
{
    const float* F   = (const float*)d_in[0];
    const float* rel = (const float*)d_in[1];
    const int*   sx  = (const int*)d_in[2];
    const int*   sy  = (const int*)d_in[3];
    const float* W1  = (const float*)d_in[4];
    const float* b1  = (const float*)d_in[5];
    const float* W2  = (const float*)d_in[6];
    const float* b2  = (const float*)d_in[7];
    const float* W3  = (const float*)d_in[8];
    const float* b3  = (const float*)d_in[9];
    const float* Wl  = (const float*)d_in[10];
    const float* bl  = (const float*)d_in[11];
    const float* cw1 = (const float*)d_in[12];
    const float* cw2 = (const float*)d_in[13];
    const float* cw3 = (const float*)d_in[14];

    const int n = in_sizes[0] / D_FEAT;   // 100000
    const int m = in_sizes[1];            // 3200000
    const int nbuck = (n + 127) >> 7;     // 782

    // workspace layout (all segments 8B-aligned)
    float*  H    = (float*)d_ws;                      // n*HID
    float*  Zp0  = H + (size_t)n * HID;               // n*ZS (also compact fallback)
    float*  Zp1  = Zp0 + (size_t)n * ZS;              // n*ZS
    ushort* Whi  = (ushort*)(Zp1 + (size_t)n * ZS);   // 262144
    ushort* Wlo  = Whi + 262144;                      // 262144
    int* deg     = (int*)(Wlo + 262144);              // n
    int* offs    = deg + n;                           // n
    int* bbase   = offs + n;                          // 1024
    int* cursor  = bbase + 1024;                      // 1024*CSTRIDE
    uint2* recs  = (uint2*)(cursor + 1024 * CSTRIDE); // 2m
    uint2* pool  = recs + 2 * (size_t)m;              // nbuck*BCAP

    const size_t need = ((char*)(pool + (size_t)nbuck * BCAP)) - (char*)d_ws;

    const int ngemm = (n + 127) / 128;          // 782
    const int nscat = (m + 4095) / 4096;        // 782
    const int nmlp  = (n + 255) / 256;          // 391
    const int g8blk = (8 * n + 255) / 256;
    const int eblk  = (m + 255) / 256;

    prep_wfrag<<<1024, 256, 0, stream>>>(W1, Whi, Wlo);

    if (ws_size >= need && nbuck <= 1024) {
        hipMemsetAsync(cursor, 0, (size_t)nbuck * CSTRIDE * sizeof(int), stream);
        // mega1: gemm ∪ scatter (overlapped on CUs)
        mega1<<<ngemm + nscat, 256, 0, stream>>>(
            F, Whi, Wlo, b1, H, n, ngemm,
            sx, sy, rel, cursor, pool, m, nbuck);
        scan_buckets<<<1, 1024, 0, stream>>>(cursor, bbase, nbuck);
        // mega2: mlp (padded Z out) ∪ sort (overlapped)
        mega2<<<nmlp + nbuck, 256, 0, stream>>>(
            H, W2, b2, W3, b3, Wl, bl, Zp0, n, nmlp, ZS,
            pool, cursor, bbase, recs, offs, deg);

        kenn_gather8<<<g8blk, 256, 0, stream>>>(Zp0, Zp1, offs, deg, recs, cw1, n, 0);
        kenn_gather8<<<g8blk, 256, 0, stream>>>(Zp1, Zp0, offs, deg, recs, cw2, n, 0);
        kenn_gather8<<<g8blk, 256, 0, stream>>>(Zp0, (float*)d_out, offs, deg, recs, cw3, n, 1);
    } else {
        // fallback: compact Z path with atomic kenn_edge
        mega1<<<ngemm, 256, 0, stream>>>(
            F, Whi, Wlo, b1, H, n, ngemm,
            sx, sy, rel, (int*)nullptr, (uint2*)nullptr, m, nbuck);
        mega2<<<nmlp, 256, 0, stream>>>(
            H, W2, b2, W3, b3, Wl, bl, Zp0, n, nmlp, NC,
            (const uint2*)nullptr, (const int*)nullptr, (const int*)nullptr,
            (uint2*)nullptr, (int*)nullptr, (int*)nullptr);

        const size_t zbytes = (size_t)n * NC * sizeof(float);
        hipMemcpyAsync(Zp1, Zp0, zbytes, hipMemcpyDeviceToDevice, stream);
        kenn_edge<<<eblk, 256, 0, stream>>>(Zp0, Zp1, rel, sx, sy, cw1, m);
        hipMemcpyAsync(Zp0, Zp1, zbytes, hipMemcpyDeviceToDevice, stream);
        kenn_edge<<<eblk, 256, 0, stream>>>(Zp1, Zp0, rel, sx, sy, cw2, m);
        hipMemcpyAsync(Zp1, Zp0, zbytes, hipMemcpyDeviceToDevice, stream);
        kenn_edge<<<eblk, 256, 0, stream>>>(Zp0, Zp1, rel, sx, sy, cw3, m);
        softmax6<<<nmlp, 256, 0, stream>>>(Zp1, (float*)d_out, n);
    }
}

// Round 13
// 757.948 us; speedup vs baseline: 1.0731x; 1.0731x over previous
//
#include <hip/hip_runtime.h>

#define D_FEAT 4096
#define HID 50
#define NC 6
#define BCAP 10240   // records per bucket region (avg ~8184)
#define CSTRIDE 16   // cursor padding: 1 counter per 64B cache line
#define ZS 8         // padded z-row stride (floats)
#define BK 32        // K-floats per staged A-chunk

typedef __attribute__((ext_vector_type(8))) short bf16x8;
typedef __attribute__((ext_vector_type(4))) float f32x4;

// ============ W1 -> bf16 hi/lo MFMA B-fragment pre-pack ============
__global__ __launch_bounds__(256) void prep_wfrag(
    const float* __restrict__ W1, ushort* __restrict__ Whi,
    ushort* __restrict__ Wlo)
{
    int idx = blockIdx.x * 256 + threadIdx.x;   // 0 .. 128*4*64*8-1
    int j  = idx & 7;
    int l  = (idx >> 3) & 63;
    int ct = (idx >> 9) & 3;
    int kc = idx >> 11;
    int k = kc * 32 + (l >> 4) * 8 + j;
    int c = ct * 16 + (l & 15);
    float v = (c < HID) ? W1[k * HID + c] : 0.f;
    unsigned b = __float_as_uint(v);
    unsigned h = (b + 0x8000u) >> 16;                 // round-half-up bf16
    float hf = __uint_as_float(h << 16);
    float lr = v - hf;
    unsigned lo = (__float_as_uint(lr) + 0x8000u) >> 16;
    Whi[idx] = (ushort)h;
    Wlo[idx] = (ushort)lo;
}

// ---- A fp32 -> bf16 hi(trunc)/lo(trunc residual), v_perm packed ----
__device__ __forceinline__ void split_a(const f32x4 a0, const f32x4 a1,
                                        bf16x8& hi, bf16x8& lo)
{
    union U4 { unsigned u[4]; bf16x8 v; } hw, lw;
#pragma unroll
    for (int p = 0; p < 4; ++p) {
        float v0 = (p < 2) ? a0[2 * p]     : a1[2 * p - 4];
        float v1 = (p < 2) ? a0[2 * p + 1] : a1[2 * p - 3];
        unsigned b0 = __float_as_uint(v0), b1 = __float_as_uint(v1);
        hw.u[p] = __builtin_amdgcn_perm(b1, b0, 0x07060302u);
        float l0f = v0 - __uint_as_float(b0 & 0xFFFF0000u);
        float l1f = v1 - __uint_as_float(b1 & 0xFFFF0000u);
        lw.u[p] = __builtin_amdgcn_perm(__float_as_uint(l1f),
                                        __float_as_uint(l0f), 0x07060302u);
    }
    hi = hw.v; lo = lw.v;
}

// ============ MEGA1: gemm blocks [0,ngemm) + scatter blocks [ngemm,..) ====
// GEMM: A staged to LDS via global_load_lds, triple-buffer, DEPTH-3
// (stage kc+3 into the buffer just consumed, guarded by a 2nd barrier).
// Top-of-iter wait vmcnt(24) = "A(kc) retired, 2 full iters of B+A in
// flight". B-loads ordered BEFORE GSTAGE so compiler's auto vmcnt for B
// registers (8) never drains the A pipeline.
__global__ __launch_bounds__(256, 3) void mega1(
    const float* __restrict__ F, const ushort* __restrict__ Whi,
    const ushort* __restrict__ Wlo, const float* __restrict__ b1,
    float* __restrict__ H, int nrows, int ngemm,
    const int* __restrict__ sx, const int* __restrict__ sy,
    const float* __restrict__ rel, int* __restrict__ cursor,
    uint2* __restrict__ pool, int m, int nbuck)
{
    __shared__ union {
        float abuf[3][128][BK];                 // 48 KB A triple-buffer
        struct { int hist[1024]; int gb[1024]; } sc;
    } u;

    if ((int)blockIdx.x < ngemm) {
        // ---------------- GEMM tile (128 rows x 64 cols) ----------------
        const int tid = threadIdx.x;
        const int w  = tid >> 6;
        const int l  = tid & 63;
        const int l16 = l & 15, lq = l >> 4;
        const long rowb = (long)blockIdx.x * 128 + (long)w * 32;
        char* abase = (char*)u.abuf;

        // staging addresses: pass p stages rows p*32+(t>>3); pre-swizzled
        // global column so linear glds writes land in swizzled LDS layout.
        const int r_lo = (tid >> 3) & 7;
        const int lc = ((tid & 7) * 16) ^ (r_lo << 4);   // logical col byte
        const float* gsrc[4];
#pragma unroll
        for (int p = 0; p < 4; ++p) {
            long rr = (long)blockIdx.x * 128 + p * 32 + (tid >> 3);
            if (rr > (long)nrows - 1) rr = (long)nrows - 1;
            gsrc[p] = F + rr * (long)D_FEAT + (lc >> 2);
        }

        // swizzled ds_read offsets (two row-tiles per wave)
        int rdoff0, rdoff1;
        { int row = w * 32 + l16;      rdoff0 = row * 128 + ((lq * 32) ^ ((row & 7) << 4)); }
        { int row = w * 32 + 16 + l16; rdoff1 = row * 128 + ((lq * 32) ^ ((row & 7) << 4)); }

        const bf16x8* bhip = (const bf16x8*)Whi + l;   // + kc*256 + ct*64
        const bf16x8* blop = (const bf16x8*)Wlo + l;

        f32x4 acc[2][4];
#pragma unroll
        for (int rt = 0; rt < 2; ++rt)
#pragma unroll
            for (int ct = 0; ct < 4; ++ct)
#pragma unroll
                for (int i = 0; i < 4; ++i) acc[rt][ct][i] = 0.f;

        bf16x8 bh[2][4], bl[2][4];

#define GSTAGE(SB, KS)                                                        \
        _Pragma("unroll")                                                     \
        for (int p = 0; p < 4; ++p)                                           \
            __builtin_amdgcn_global_load_lds(                                 \
                (const __attribute__((address_space(1))) void*)(gsrc[p] + (KS) * BK), \
                (__attribute__((address_space(3))) void*)(abase + (SB) * 16384 + p * 4096 + w * 1024), \
                16, 0, 0);

        // prologue: stage A(0),A(1),A(2); B(0)->set0
        GSTAGE(0, 0)
        __builtin_amdgcn_sched_barrier(0);
        GSTAGE(1, 1)
        __builtin_amdgcn_sched_barrier(0);
        GSTAGE(2, 2)
        __builtin_amdgcn_sched_barrier(0);
#pragma unroll
        for (int ct = 0; ct < 4; ++ct) { bh[0][ct] = bhip[ct * 64]; bl[0][ct] = blop[ct * 64]; }

// ITER: consume A(KC) from buf KC%3 + B set KC&1; load B(KC+1)->set BN;
// restage buf with A(KC+3) after barrier2. VC: ops newer than A(KC)-stage.
#define ITER(KC, BUF, BC, BN, VC)                                             \
        {                                                                     \
            asm volatile("s_waitcnt vmcnt(" #VC ")" ::: "memory");            \
            __builtin_amdgcn_s_barrier();                                     \
            __builtin_amdgcn_sched_barrier(0);                                \
            f32x4 a00 = *(const f32x4*)(abase + (BUF) * 16384 + rdoff0);      \
            f32x4 a01 = *(const f32x4*)(abase + (BUF) * 16384 + (rdoff0 ^ 16)); \
            f32x4 a10 = *(const f32x4*)(abase + (BUF) * 16384 + rdoff1);      \
            f32x4 a11 = *(const f32x4*)(abase + (BUF) * 16384 + (rdoff1 ^ 16)); \
            asm volatile("s_waitcnt lgkmcnt(0)" ::: "memory");                \
            __builtin_amdgcn_sched_barrier(0);                                \
            __builtin_amdgcn_s_barrier();                                     \
            __builtin_amdgcn_sched_barrier(0);                                \
            const int kb_ = ((KC) + 1 <= 127) ? (KC) + 1 : 127;               \
            _Pragma("unroll")                                                 \
            for (int ct = 0; ct < 4; ++ct) {                                  \
                bh[BN][ct] = bhip[kb_ * 256 + ct * 64];                       \
                bl[BN][ct] = blop[kb_ * 256 + ct * 64];                       \
            }                                                                 \
            __builtin_amdgcn_sched_barrier(0);                                \
            const int ks_ = ((KC) + 3 <= 127) ? (KC) + 3 : 127;               \
            GSTAGE(BUF, ks_)                                                  \
            __builtin_amdgcn_sched_barrier(0);                                \
            bf16x8 ahi0, alo0, ahi1, alo1;                                    \
            split_a(a00, a01, ahi0, alo0);                                    \
            split_a(a10, a11, ahi1, alo1);                                    \
            _Pragma("unroll")                                                 \
            for (int ct = 0; ct < 4; ++ct) {                                  \
                acc[0][ct] = __builtin_amdgcn_mfma_f32_16x16x32_bf16(ahi0, bh[BC][ct], acc[0][ct], 0, 0, 0); \
                acc[0][ct] = __builtin_amdgcn_mfma_f32_16x16x32_bf16(ahi0, bl[BC][ct], acc[0][ct], 0, 0, 0); \
                acc[0][ct] = __builtin_amdgcn_mfma_f32_16x16x32_bf16(alo0, bh[BC][ct], acc[0][ct], 0, 0, 0); \
                acc[1][ct] = __builtin_amdgcn_mfma_f32_16x16x32_bf16(ahi1, bh[BC][ct], acc[1][ct], 0, 0, 0); \
                acc[1][ct] = __builtin_amdgcn_mfma_f32_16x16x32_bf16(ahi1, bl[BC][ct], acc[1][ct], 0, 0, 0); \
                acc[1][ct] = __builtin_amdgcn_mfma_f32_16x16x32_bf16(alo1, bh[BC][ct], acc[1][ct], 0, 0, 0); \
            }                                                                 \
        }

        // peeled prologue (exact counts: 8, 16, then steady 24)
        ITER(0, 0, 0, 1, 8)
        ITER(1, 1, 1, 0, 16)
        ITER(2, 2, 0, 1, 24)

        // main loop: period-6 (3 bufs x 2 B-sets); kk = 3..117
#pragma unroll 1
        for (int kk = 3; kk <= 117; kk += 6) {
            ITER(kk + 0, 0, 1, 0, 24)
            ITER(kk + 1, 1, 0, 1, 24)
            ITER(kk + 2, 2, 1, 0, 24)
            ITER(kk + 3, 0, 0, 1, 24)
            ITER(kk + 4, 1, 1, 0, 24)
            ITER(kk + 5, 2, 0, 1, 24)
        }
        // tail: 123..127
        ITER(123, 0, 1, 0, 24)
        ITER(124, 1, 0, 1, 24)
        ITER(125, 2, 1, 0, 24)
        ITER(126, 0, 0, 1, 24)
        ITER(127, 1, 1, 0, 24)
#undef ITER
#undef GSTAGE

        // epilogue: D row = (lane>>4)*4 + i, col = ct*16 + (lane&15)
#pragma unroll
        for (int ct = 0; ct < 4; ++ct) {
            int col = ct * 16 + l16;
            if (col >= HID) continue;
            float bias = b1[col];
#pragma unroll
            for (int rt = 0; rt < 2; ++rt)
#pragma unroll
                for (int i = 0; i < 4; ++i) {
                    long row = rowb + rt * 16 + lq * 4 + i;
                    if (row < nrows) {
                        float v = acc[rt][ct][i] + bias;
                        H[row * HID + col] = v > 0.f ? v : 0.f;
                    }
                }
        }
    } else {
        // ------------- scatter-bucket tile (4096 edges, rank-only regs) ----
        const int bid = blockIdx.x - ngemm;
        const int t = threadIdx.x;
        for (int i = t; i < 1024; i += 256) u.sc.hist[i] = 0;
        __syncthreads();

        const int e0 = bid * 4096;
        unsigned prA[16], prB[16];
#pragma unroll
        for (int k = 0; k < 16; ++k) {
            int e = e0 + k * 256 + t;
            if (e < m) {
                int x = sx[e], y = sy[e];
                int bA = x >> 7;
                prA[k] = ((unsigned)bA << 22) | (unsigned)atomicAdd(&u.sc.hist[bA], 1);
                int bB = y >> 7;
                prB[k] = ((unsigned)bB << 22) | (unsigned)atomicAdd(&u.sc.hist[bB], 1);
            } else {
                prA[k] = 0xFFFFFFFFu; prB[k] = 0xFFFFFFFFu;
            }
        }
        __syncthreads();
        for (int b = t; b < nbuck; b += 256) {
            int h = u.sc.hist[b];
            u.sc.gb[b] = h ? atomicAdd(&cursor[b * CSTRIDE], h) : 0;
        }
        __syncthreads();
#pragma unroll
        for (int k = 0; k < 16; ++k) {
            if (prA[k] == 0xFFFFFFFFu) continue;
            int e = e0 + k * 256 + t;
            int x = sx[e], y = sy[e];               // L2-hot re-read
            unsigned rb = __float_as_uint(rel[e]);
            {
                unsigned buck = prA[k] >> 22, rank = prA[k] & 0x3FFFFFu;
                unsigned slot = (unsigned)u.sc.gb[buck] + rank;
                if (slot < BCAP)
                    pool[(size_t)buck * BCAP + slot] =
                        make_uint2((unsigned)(x & 127) | ((unsigned)y << 8), rb);
            }
            {
                unsigned buck = prB[k] >> 22, rank = prB[k] & 0x3FFFFFu;
                unsigned slot = (unsigned)u.sc.gb[buck] + rank;
                if (slot < BCAP)
                    pool[(size_t)buck * BCAP + slot] =
                        make_uint2((unsigned)(y & 127) | 0x80u | ((unsigned)x << 8), rb);
            }
        }
    }
}

// exclusive scan of clamped bucket counts (nb <= 1024)
__global__ __launch_bounds__(1024) void scan_buckets(
    const int* __restrict__ cursor, int* __restrict__ bucket_base, int nb)
{
    __shared__ int s[1024];
    int t = threadIdx.x;
    int v = 0;
    if (t < nb) { v = cursor[t * CSTRIDE]; if (v > BCAP) v = BCAP; }
    s[t] = v;
    __syncthreads();
    for (int st = 1; st < 1024; st <<= 1) {
        int tmp = (t >= st) ? s[t - st] : 0;
        __syncthreads();
        s[t] += tmp;
        __syncthreads();
    }
    if (t < nb) bucket_base[t] = s[t] - v;
}

// ============ MEGA2: mlp blocks [0,nmlp) + sort blocks [nmlp,..) ============
__global__ __launch_bounds__(256) void mega2(
    const float* __restrict__ H,
    const float* __restrict__ W2, const float* __restrict__ b2,
    const float* __restrict__ W3, const float* __restrict__ b3,
    const float* __restrict__ Wl, const float* __restrict__ bl,
    float* __restrict__ Z, int n, int nmlp, int zs,
    const uint2* __restrict__ pool, const int* __restrict__ cursor,
    const int* __restrict__ bucket_base, uint2* __restrict__ recs,
    int* __restrict__ offs, int* __restrict__ deg)
{
    __shared__ union {
        struct {
            float w2[HID][52];
            float w3[HID][52];
            float wl[52][8];
            float bb2[52], bb3[52], bbl[8];
        } mlp;
        struct {
            int hist[128], nbase[128], cur[128], sc[128];
            ushort ord[BCAP];
        } srt;
    } u;

    if ((int)blockIdx.x < nmlp) {
        // ---------------- MLP tail ----------------
        for (int i = threadIdx.x; i < HID * 52; i += 256) {
            int r = i / 52, c = i % 52;
            u.mlp.w2[r][c] = (c < HID) ? W2[r * HID + c] : 0.f;
            u.mlp.w3[r][c] = (c < HID) ? W3[r * HID + c] : 0.f;
        }
        for (int i = threadIdx.x; i < 52 * 8; i += 256) {
            int r = i / 8, c = i % 8;
            u.mlp.wl[r][c] = (r < HID && c < NC) ? Wl[r * NC + c] : 0.f;
        }
        if (threadIdx.x < 52) {
            u.mlp.bb2[threadIdx.x] = (threadIdx.x < HID) ? b2[threadIdx.x] : 0.f;
            u.mlp.bb3[threadIdx.x] = (threadIdx.x < HID) ? b3[threadIdx.x] : 0.f;
        }
        if (threadIdx.x < 8) u.mlp.bbl[threadIdx.x] = (threadIdx.x < NC) ? bl[threadIdx.x] : 0.f;
        __syncthreads();

        long row = (long)blockIdx.x * 256 + threadIdx.x;
        if (row >= n) return;

        float x1[HID];
#pragma unroll
        for (int i = 0; i < HID / 2; ++i) {
            float2 t = *(const float2*)(H + row * HID + 2 * i);
            x1[2 * i] = t.x; x1[2 * i + 1] = t.y;
        }

        float x2[52];
#pragma unroll
        for (int j = 0; j < 52; ++j) x2[j] = u.mlp.bb2[j];
        for (int i = 0; i < HID; ++i) {
            float xi = x1[i];
#pragma unroll
            for (int jq = 0; jq < 13; ++jq) {
                float4 t = *(const float4*)&u.mlp.w2[i][jq * 4];
                x2[jq * 4 + 0] = fmaf(xi, t.x, x2[jq * 4 + 0]);
                x2[jq * 4 + 1] = fmaf(xi, t.y, x2[jq * 4 + 1]);
                x2[jq * 4 + 2] = fmaf(xi, t.z, x2[jq * 4 + 2]);
                x2[jq * 4 + 3] = fmaf(xi, t.w, x2[jq * 4 + 3]);
            }
        }
#pragma unroll
        for (int j = 0; j < 52; ++j) x2[j] = fmaxf(x2[j], 0.f);

        float z[NC];
#pragma unroll
        for (int c = 0; c < NC; ++c) z[c] = u.mlp.bbl[c];
        for (int jq = 0; jq < 13; ++jq) {
            float t0 = u.mlp.bb3[jq * 4 + 0], t1 = u.mlp.bb3[jq * 4 + 1];
            float t2 = u.mlp.bb3[jq * 4 + 2], t3 = u.mlp.bb3[jq * 4 + 3];
            for (int k = 0; k < HID; ++k) {
                float xk = x2[k];
                float4 wv = *(const float4*)&u.mlp.w3[k][jq * 4];
                t0 = fmaf(xk, wv.x, t0);
                t1 = fmaf(xk, wv.y, t1);
                t2 = fmaf(xk, wv.z, t2);
                t3 = fmaf(xk, wv.w, t3);
            }
            t0 = fmaxf(t0, 0.f); t1 = fmaxf(t1, 0.f);
            t2 = fmaxf(t2, 0.f); t3 = fmaxf(t3, 0.f);
#pragma unroll
            for (int c = 0; c < NC; ++c) {
                z[c] = fmaf(t0, u.mlp.wl[jq * 4 + 0][c], z[c]);
                z[c] = fmaf(t1, u.mlp.wl[jq * 4 + 1][c], z[c]);
                z[c] = fmaf(t2, u.mlp.wl[jq * 4 + 2][c], z[c]);
                z[c] = fmaf(t3, u.mlp.wl[jq * 4 + 3][c], z[c]);
            }
        }
        if (zs == ZS) {
            float* po = Z + (size_t)ZS * row;
            *(float4*)po       = make_float4(z[0], z[1], z[2], z[3]);
            *(float4*)(po + 4) = make_float4(z[4], z[5], 0.f, 0.f);
        } else {
#pragma unroll
            for (int c = 0; c < NC; ++c) Z[row * NC + c] = z[c];
        }
    } else {
        // ---------------- per-bucket counting sort ----------------
        const int b = blockIdx.x - nmlp;
        const int t = threadIdx.x;
        int cnt = cursor[b * CSTRIDE]; if (cnt > BCAP) cnt = BCAP;
        const int base = bucket_base[b];
        if (t < 128) u.srt.hist[t] = 0;
        __syncthreads();
        const uint2* bp = pool + (size_t)b * BCAP;
        for (int i = t; i < cnt; i += 256)
            atomicAdd(&u.srt.hist[bp[i].x & 127u], 1);
        __syncthreads();
        int v = (t < 128) ? u.srt.hist[t] : 0;
        if (t < 128) u.srt.sc[t] = v;
        __syncthreads();
        for (int st = 1; st < 128; st <<= 1) {
            int tmp = (t >= st && t < 128) ? u.srt.sc[t - st] : 0;
            __syncthreads();
            if (t < 128) u.srt.sc[t] += tmp;
            __syncthreads();
        }
        if (t < 128) {
            u.srt.nbase[t] = u.srt.sc[t] - v;
            u.srt.cur[t] = 0;
            int gnode = b * 128 + t;
            if (gnode < n) { offs[gnode] = base + u.srt.sc[t] - v; deg[gnode] = v; }
        }
        __syncthreads();
        for (int i = t; i < cnt; i += 256) {
            unsigned nl = bp[i].x & 127u;
            int rk = atomicAdd(&u.srt.cur[nl], 1);
            u.srt.ord[u.srt.nbase[nl] + rk] = (ushort)i;
        }
        __syncthreads();
        for (int i = t; i < cnt; i += 256) {
            uint2 r = bp[u.srt.ord[i]];
            unsigned side = (r.x >> 7) & 1u;
            unsigned other = r.x >> 8;
            recs[base + i] = make_uint2(other | (side << 31), r.y);
        }
    }
}

// ============ KENN layer: 8 lanes per node, shfl reduce, padded Z ============
__global__ __launch_bounds__(256) void kenn_gather8(
    const float* __restrict__ Zin, float* __restrict__ Zout,
    const int* __restrict__ offs, const int* __restrict__ deg,
    const uint2* __restrict__ recs, const float* __restrict__ cw,
    int n, int dofinal)
{
    int gt = blockIdx.x * 256 + threadIdx.x;
    int node = gt >> 3;
    int l8 = gt & 7;
    if (node >= n) return;

    float4 za = *(const float4*)(Zin + (size_t)ZS * node);
    float4 zb = *(const float4*)(Zin + (size_t)ZS * node + 4);
    float zown[NC] = { za.x, za.y, za.z, za.w, zb.x, zb.y };
    float acc[NC], cwv[NC];
#pragma unroll
    for (int c = 0; c < NC; ++c) { acc[c] = 0.f; cwv[c] = cw[c]; }

    const int start = offs[node];
    const int cnt = deg[node];

#pragma unroll 2
    for (int i = l8; i < cnt; i += 8) {
        uint2 rc = recs[start + i];
        const int other = (int)(rc.x & 0x7FFFFFFFu);
        const bool sideY = (rc.x & 0x80000000u) != 0;
        const float l0 = -__uint_as_float(rc.y);

        float4 oa = *(const float4*)(Zin + (size_t)ZS * other);
        float4 ob = *(const float4*)(Zin + (size_t)ZS * other + 4);
        float zo[NC] = { oa.x, oa.y, oa.z, oa.w, ob.x, ob.y };

#pragma unroll
        for (int c = 0; c < NC; ++c) {
            float zx = sideY ? zo[c] : zown[c];
            float zy = sideY ? zown[c] : zo[c];
            float l1 = -zx;
            float l2 = zy;
            float mx = fmaxf(l0, fmaxf(l1, l2));
            float e0 = __expf(l0 - mx);
            float e1 = __expf(l1 - mx);
            float e2 = __expf(l2 - mx);
            float g = cwv[c] * __builtin_amdgcn_rcpf(e0 + e1 + e2);
            acc[c] += sideY ? (e2 * g) : (-e1 * g);
        }
    }

#pragma unroll
    for (int c = 0; c < NC; ++c) {
        acc[c] += __shfl_xor(acc[c], 1, 64);
        acc[c] += __shfl_xor(acc[c], 2, 64);
        acc[c] += __shfl_xor(acc[c], 4, 64);
    }

    if (l8 != 0) return;

#pragma unroll
    for (int c = 0; c < NC; ++c) acc[c] += zown[c];

    if (dofinal) {
        float mx = acc[0];
#pragma unroll
        for (int c = 1; c < NC; ++c) mx = fmaxf(mx, acc[c]);
        float e[NC], s = 0.f;
#pragma unroll
        for (int c = 0; c < NC; ++c) { e[c] = __expf(acc[c] - mx); s += e[c]; }
        float inv = 1.f / s;
        float2* po = (float2*)(Zout + 6L * node);   // compact output
#pragma unroll
        for (int q = 0; q < 3; ++q) {
            float2 t; t.x = e[2 * q] * inv; t.y = e[2 * q + 1] * inv;
            po[q] = t;
        }
    } else {
        float* po = Zout + (size_t)ZS * node;
        *(float4*)po       = make_float4(acc[0], acc[1], acc[2], acc[3]);
        *(float4*)(po + 4) = make_float4(acc[4], acc[5], 0.f, 0.f);
    }
}

// ---------------- fallback path kernels (atomic version, compact Z) --------
__global__ __launch_bounds__(256) void kenn_edge(
    const float* __restrict__ Zold, float* __restrict__ Znew,
    const float* __restrict__ rel, const int* __restrict__ sx,
    const int* __restrict__ sy, const float* __restrict__ cw, int m)
{
    int idx = blockIdx.x * 256 + threadIdx.x;
    if (idx >= m) return;
    const int x = sx[idx];
    const int y = sy[idx];
    const float l0 = -rel[idx];

    float zx[NC], zy[NC];
    const float2* px = (const float2*)(Zold + 6L * x);
    const float2* py = (const float2*)(Zold + 6L * y);
#pragma unroll
    for (int q = 0; q < 3; ++q) {
        float2 t = px[q]; zx[2 * q] = t.x; zx[2 * q + 1] = t.y;
        float2 u = py[q]; zy[2 * q] = u.x; zy[2 * q + 1] = u.y;
    }
#pragma unroll
    for (int c = 0; c < NC; ++c) {
        float l1 = -zx[c];
        float l2 = zy[c];
        float mx = fmaxf(l0, fmaxf(l1, l2));
        float e0 = __expf(l0 - mx);
        float e1 = __expf(l1 - mx);
        float e2 = __expf(l2 - mx);
        float s = cw[c] / (e0 + e1 + e2);
        atomicAdd(&Znew[6L * x + c], -e1 * s);
        atomicAdd(&Znew[6L * y + c],  e2 * s);
    }
}

__global__ __launch_bounds__(256) void softmax6(
    const float* __restrict__ Z, float* __restrict__ out, int n)
{
    long row = (long)blockIdx.x * 256 + threadIdx.x;
    if (row >= n) return;
    float v[NC];
    const float2* p = (const float2*)(Z + row * 6);
#pragma unroll
    for (int q = 0; q < 3; ++q) { float2 t = p[q]; v[2 * q] = t.x; v[2 * q + 1] = t.y; }
    float mx = v[0];
#pragma unroll
    for (int c = 1; c < NC; ++c) mx = fmaxf(mx, v[c]);
    float e[NC], s = 0.f;
#pragma unroll
    for (int c = 0; c < NC; ++c) { e[c] = __expf(v[c] - mx); s += e[c]; }
    float inv = 1.f / s;
    float2* po = (float2*)(out + row * 6);
#pragma unroll
    for (int q = 0; q < 3; ++q) {
        float2 t; t.x = e[2 * q] * inv; t.y = e[2 * q + 1] * inv;
        po[q] = t;
    }
}

extern "C" void kernel_launch(void* const* d_in, const int* in_sizes, int n_in,
                              void* d_out, int out_size, void* d_ws, size_t ws_size,
                              hipStream_t stream)
{
    const float* F   = (const float*)d_in[0];
    const float* rel = (const float*)d_in[1];
    const int*   sx  = (const int*)d_in[2];
    const int*   sy  = (const int*)d_in[3];
    const float* W1  = (const float*)d_in[4];
    const float* b1  = (const float*)d_in[5];
    const float* W2  = (const float*)d_in[6];
    const float* b2  = (const float*)d_in[7];
    const float* W3  = (const float*)d_in[8];
    const float* b3  = (const float*)d_in[9];
    const float* Wl  = (const float*)d_in[10];
    const float* bl  = (const float*)d_in[11];
    const float* cw1 = (const float*)d_in[12];
    const float* cw2 = (const float*)d_in[13];
    const float* cw3 = (const float*)d_in[14];

    const int n = in_sizes[0] / D_FEAT;   // 100000
    const int m = in_sizes[1];            // 3200000
    const int nbuck = (n + 127) >> 7;     // 782

    // workspace layout (all segments 8B-aligned)
    float*  H    = (float*)d_ws;                      // n*HID
    float*  Zp0  = H + (size_t)n * HID;               // n*ZS (also compact fallback)
    float*  Zp1  = Zp0 + (size_t)n * ZS;              // n*ZS
    ushort* Whi  = (ushort*)(Zp1 + (size_t)n * ZS);   // 262144
    ushort* Wlo  = Whi + 262144;                      // 262144
    int* deg     = (int*)(Wlo + 262144);              // n
    int* offs    = deg + n;                           // n
    int* bbase   = offs + n;                          // 1024
    int* cursor  = bbase + 1024;                      // 1024*CSTRIDE
    uint2* recs  = (uint2*)(cursor + 1024 * CSTRIDE); // 2m
    uint2* pool  = recs + 2 * (size_t)m;              // nbuck*BCAP

    const size_t need = ((char*)(pool + (size_t)nbuck * BCAP)) - (char*)d_ws;

    const int ngemm = (n + 127) / 128;          // 782
    const int nscat = (m + 4095) / 4096;        // 782
    const int nmlp  = (n + 255) / 256;          // 391
    const int g8blk = (8 * n + 255) / 256;
    const int eblk  = (m + 255) / 256;

    prep_wfrag<<<1024, 256, 0, stream>>>(W1, Whi, Wlo);

    if (ws_size >= need && nbuck <= 1024) {
        hipMemsetAsync(cursor, 0, (size_t)nbuck * CSTRIDE * sizeof(int), stream);
        // mega1: gemm ∪ scatter (overlapped on CUs)
        mega1<<<ngemm + nscat, 256, 0, stream>>>(
            F, Whi, Wlo, b1, H, n, ngemm,
            sx, sy, rel, cursor, pool, m, nbuck);
        scan_buckets<<<1, 1024, 0, stream>>>(cursor, bbase, nbuck);
        // mega2: mlp (padded Z out) ∪ sort (overlapped)
        mega2<<<nmlp + nbuck, 256, 0, stream>>>(
            H, W2, b2, W3, b3, Wl, bl, Zp0, n, nmlp, ZS,
            pool, cursor, bbase, recs, offs, deg);

        kenn_gather8<<<g8blk, 256, 0, stream>>>(Zp0, Zp1, offs, deg, recs, cw1, n, 0);
        kenn_gather8<<<g8blk, 256, 0, stream>>>(Zp1, Zp0, offs, deg, recs, cw2, n, 0);
        kenn_gather8<<<g8blk, 256, 0, stream>>>(Zp0, (float*)d_out, offs, deg, recs, cw3, n, 1);
    } else {
        // fallback: compact Z path with atomic kenn_edge
        mega1<<<ngemm, 256, 0, stream>>>(
            F, Whi, Wlo, b1, H, n, ngemm,
            sx, sy, rel, (int*)nullptr, (uint2*)nullptr, m, nbuck);
        mega2<<<nmlp, 256, 0, stream>>>(
            H, W2, b2, W3, b3, Wl, bl, Zp0, n, nmlp, NC,
            (const uint2*)nullptr, (const int*)nullptr, (const int*)nullptr,
            (uint2*)nullptr, (int*)nullptr, (int*)nullptr);

        const size_t zbytes = (size_t)n * NC * sizeof(float);
        hipMemcpyAsync(Zp1, Zp0, zbytes, hipMemcpyDeviceToDevice, stream);
        kenn_edge<<<eblk, 256, 0, stream>>>(Zp0, Zp1, rel, sx, sy, cw1, m);
        hipMemcpyAsync(Zp0, Zp1, zbytes, hipMemcpyDeviceToDevice, stream);
        kenn_edge<<<eblk, 256, 0, stream>>>(Zp1, Zp0, rel, sx, sy, cw2, m);
        hipMemcpyAsync(Zp1, Zp0, zbytes, hipMemcpyDeviceToDevice, stream);
        kenn_edge<<<eblk, 256, 0, stream>>>(Zp0, Zp1, rel, sx, sy, cw3, m);
        softmax6<<<nmlp, 256, 0, stream>>>(Zp1, (float*)d_out, n);
    }
}

// Round 14
// 748.450 us; speedup vs baseline: 1.0868x; 1.0127x over previous
//
#include <hip/hip_runtime.h>

#define D_FEAT 4096
#define HID 50
#define NC 6
#define BCAP 10240   // records per bucket region (avg ~8184)
#define CSTRIDE 16   // cursor padding: 1 counter per 64B cache line
#define ZS 8         // padded z-row stride (floats)

typedef __attribute__((ext_vector_type(8))) short bf16x8;
typedef __attribute__((ext_vector_type(4))) float f32x4;

// ============ W1 -> bf16 hi/lo MFMA B-fragment pre-pack ============
__global__ __launch_bounds__(256) void prep_wfrag(
    const float* __restrict__ W1, ushort* __restrict__ Whi,
    ushort* __restrict__ Wlo)
{
    int idx = blockIdx.x * 256 + threadIdx.x;   // 0 .. 128*4*64*8-1
    int j  = idx & 7;
    int l  = (idx >> 3) & 63;
    int ct = (idx >> 9) & 3;
    int kc = idx >> 11;
    int k = kc * 32 + (l >> 4) * 8 + j;
    int c = ct * 16 + (l & 15);
    float v = (c < HID) ? W1[k * HID + c] : 0.f;
    unsigned b = __float_as_uint(v);
    unsigned h = (b + 0x8000u) >> 16;                 // round-half-up bf16
    float hf = __uint_as_float(h << 16);
    float lr = v - hf;
    unsigned lo = (__float_as_uint(lr) + 0x8000u) >> 16;
    Whi[idx] = (ushort)h;
    Wlo[idx] = (ushort)lo;
}

// ---- A fp32 -> bf16 hi(trunc)/lo(trunc residual), v_perm packed ----
__device__ __forceinline__ void split_a(const f32x4 a0, const f32x4 a1,
                                        bf16x8& hi, bf16x8& lo)
{
    union U4 { unsigned u[4]; bf16x8 v; } hw, lw;
#pragma unroll
    for (int p = 0; p < 4; ++p) {
        float v0 = (p < 2) ? a0[2 * p]     : a1[2 * p - 4];
        float v1 = (p < 2) ? a0[2 * p + 1] : a1[2 * p - 3];
        unsigned b0 = __float_as_uint(v0), b1 = __float_as_uint(v1);
        hw.u[p] = __builtin_amdgcn_perm(b1, b0, 0x07060302u);
        float l0f = v0 - __uint_as_float(b0 & 0xFFFF0000u);
        float l1f = v1 - __uint_as_float(b1 & 0xFFFF0000u);
        lw.u[p] = __builtin_amdgcn_perm(__float_as_uint(l1f),
                                        __float_as_uint(l0f), 0x07060302u);
    }
    hi = hw.v; lo = lw.v;
}

// ============ MEGA1: gemm blocks [0,ngemm) + scatter blocks [ngemm,..) ====
// GEMM: BK=64 staging — each global_load_lds covers 4 rows x 256 B
// CONTIGUOUS (vs 8 rows x 128 B before): doubles per-row DRAM burst to
// fix pattern-limited HBM efficiency. 2 x 32 KB double buffer, one
// barrier+vmcnt(0) per 2-kc iteration. 16-slot XOR swizzle both sides.
__global__ __launch_bounds__(256, 2) void mega1(
    const float* __restrict__ F, const ushort* __restrict__ Whi,
    const ushort* __restrict__ Wlo, const float* __restrict__ b1,
    float* __restrict__ H, int nrows, int ngemm,
    const int* __restrict__ sx, const int* __restrict__ sy,
    const float* __restrict__ rel, int* __restrict__ cursor,
    uint2* __restrict__ pool, int m, int nbuck)
{
    __shared__ union {
        float abuf[2][128][64];                 // 64 KB A double-buffer
        struct { int hist[1024]; int gb[1024]; } sc;
    } u;

    if ((int)blockIdx.x < ngemm) {
        // ---------------- GEMM tile (128 rows x 64 cols) ----------------
        const int tid = threadIdx.x;
        const int w  = tid >> 6;
        const int l  = tid & 63;
        const int l16 = l & 15, lq = l >> 4;
        const long rowb = (long)blockIdx.x * 128 + (long)w * 32;
        char* abase = (char*)u.abuf;

        // staging: glds inst p covers rows p*16 + w*4 + (l>>4), slot l&15.
        // pre-swizzled global col: logical_slot = (l&15) ^ (row&15).
        const int gcol = ((l & 15) ^ ((w * 4 + (l >> 4)) & 15)) * 4;
        const float* gsrc[8];
#pragma unroll
        for (int p = 0; p < 8; ++p) {
            long rr = (long)blockIdx.x * 128 + p * 16 + w * 4 + (l >> 4);
            if (rr > (long)nrows - 1) rr = (long)nrows - 1;
            gsrc[p] = F + rr * (long)D_FEAT + gcol;
        }

        // swizzled ds_read offsets: rd[rt][h][s]; row&15 == l16
        int rd[2][2][2];
#pragma unroll
        for (int rt = 0; rt < 2; ++rt)
#pragma unroll
            for (int h = 0; h < 2; ++h)
#pragma unroll
                for (int s = 0; s < 2; ++s)
                    rd[rt][h][s] = (w * 32 + rt * 16 + l16) * 256 +
                                   (((h * 8 + lq * 2 + s) ^ l16) << 4);

        const bf16x8* bhip = (const bf16x8*)Whi + l;   // + kc*256 + ct*64
        const bf16x8* blop = (const bf16x8*)Wlo + l;

        f32x4 acc[2][4];
#pragma unroll
        for (int rt = 0; rt < 2; ++rt)
#pragma unroll
            for (int ct = 0; ct < 4; ++ct)
#pragma unroll
                for (int i = 0; i < 4; ++i) acc[rt][ct][i] = 0.f;

        bf16x8 bh0[4], bl0[4], bh1[4], bl1[4];

#define GSTAGE(SB, KS)                                                        \
        _Pragma("unroll")                                                     \
        for (int p = 0; p < 8; ++p)                                           \
            __builtin_amdgcn_global_load_lds(                                 \
                (const __attribute__((address_space(1))) void*)(gsrc[p] + (long)(KS) * 64), \
                (__attribute__((address_space(3))) void*)(abase + (SB) * 32768 + p * 4096 + w * 1024), \
                16, 0, 0);

        // prologue: stage chunk 0 -> buf 0; B(0) -> set0
        GSTAGE(0, 0)
#pragma unroll
        for (int ct = 0; ct < 4; ++ct) { bh0[ct] = bhip[ct * 64]; bl0[ct] = blop[ct * 64]; }

// ITER J: consume buf CB (chunk J = kcs 2J,2J+1); stage chunk J+1 -> CB^1.
// Order: drain, barrier, ds_reads, B(2J+1)->set1, GSTAGE, MFMA kc0(set0),
// B(2J+2)->set0, MFMA kc1(set1).
#define ITER(J, CB)                                                           \
        {                                                                     \
            asm volatile("s_waitcnt vmcnt(0)" ::: "memory");                  \
            __builtin_amdgcn_sched_barrier(0);                                \
            __builtin_amdgcn_s_barrier();                                     \
            __builtin_amdgcn_sched_barrier(0);                                \
            const char* rb_ = abase + (CB) * 32768;                           \
            f32x4 aA0 = *(const f32x4*)(rb_ + rd[0][0][0]);                   \
            f32x4 aA1 = *(const f32x4*)(rb_ + rd[0][0][1]);                   \
            f32x4 aB0 = *(const f32x4*)(rb_ + rd[1][0][0]);                   \
            f32x4 aB1 = *(const f32x4*)(rb_ + rd[1][0][1]);                   \
            f32x4 aC0 = *(const f32x4*)(rb_ + rd[0][1][0]);                   \
            f32x4 aC1 = *(const f32x4*)(rb_ + rd[0][1][1]);                   \
            f32x4 aD0 = *(const f32x4*)(rb_ + rd[1][1][0]);                   \
            f32x4 aD1 = *(const f32x4*)(rb_ + rd[1][1][1]);                   \
            const int kb1_ = (2 * (J) + 1 <= 127) ? 2 * (J) + 1 : 127;        \
            _Pragma("unroll")                                                 \
            for (int ct = 0; ct < 4; ++ct) {                                  \
                bh1[ct] = bhip[kb1_ * 256 + ct * 64];                         \
                bl1[ct] = blop[kb1_ * 256 + ct * 64];                         \
            }                                                                 \
            __builtin_amdgcn_sched_barrier(0);                                \
            const int ks_ = ((J) + 1 <= 63) ? (J) + 1 : 63;                   \
            GSTAGE((CB) ^ 1, ks_)                                             \
            __builtin_amdgcn_sched_barrier(0);                                \
            {                                                                 \
                bf16x8 h0, lo0, h1, lo1;                                      \
                split_a(aA0, aA1, h0, lo0);                                   \
                split_a(aB0, aB1, h1, lo1);                                   \
                _Pragma("unroll")                                             \
                for (int ct = 0; ct < 4; ++ct) {                              \
                    acc[0][ct] = __builtin_amdgcn_mfma_f32_16x16x32_bf16(h0, bh0[ct], acc[0][ct], 0, 0, 0); \
                    acc[0][ct] = __builtin_amdgcn_mfma_f32_16x16x32_bf16(h0, bl0[ct], acc[0][ct], 0, 0, 0); \
                    acc[0][ct] = __builtin_amdgcn_mfma_f32_16x16x32_bf16(lo0, bh0[ct], acc[0][ct], 0, 0, 0); \
                    acc[1][ct] = __builtin_amdgcn_mfma_f32_16x16x32_bf16(h1, bh0[ct], acc[1][ct], 0, 0, 0); \
                    acc[1][ct] = __builtin_amdgcn_mfma_f32_16x16x32_bf16(h1, bl0[ct], acc[1][ct], 0, 0, 0); \
                    acc[1][ct] = __builtin_amdgcn_mfma_f32_16x16x32_bf16(lo1, bh0[ct], acc[1][ct], 0, 0, 0); \
                }                                                             \
            }                                                                 \
            const int kb2_ = (2 * (J) + 2 <= 127) ? 2 * (J) + 2 : 127;        \
            _Pragma("unroll")                                                 \
            for (int ct = 0; ct < 4; ++ct) {                                  \
                bh0[ct] = bhip[kb2_ * 256 + ct * 64];                         \
                bl0[ct] = blop[kb2_ * 256 + ct * 64];                         \
            }                                                                 \
            {                                                                 \
                bf16x8 h0, lo0, h1, lo1;                                      \
                split_a(aC0, aC1, h0, lo0);                                   \
                split_a(aD0, aD1, h1, lo1);                                   \
                _Pragma("unroll")                                             \
                for (int ct = 0; ct < 4; ++ct) {                              \
                    acc[0][ct] = __builtin_amdgcn_mfma_f32_16x16x32_bf16(h0, bh1[ct], acc[0][ct], 0, 0, 0); \
                    acc[0][ct] = __builtin_amdgcn_mfma_f32_16x16x32_bf16(h0, bl1[ct], acc[0][ct], 0, 0, 0); \
                    acc[0][ct] = __builtin_amdgcn_mfma_f32_16x16x32_bf16(lo0, bh1[ct], acc[0][ct], 0, 0, 0); \
                    acc[1][ct] = __builtin_amdgcn_mfma_f32_16x16x32_bf16(h1, bh1[ct], acc[1][ct], 0, 0, 0); \
                    acc[1][ct] = __builtin_amdgcn_mfma_f32_16x16x32_bf16(h1, bl1[ct], acc[1][ct], 0, 0, 0); \
                    acc[1][ct] = __builtin_amdgcn_mfma_f32_16x16x32_bf16(lo1, bh1[ct], acc[1][ct], 0, 0, 0); \
                }                                                             \
            }                                                                 \
        }

#pragma unroll 1
        for (int j = 0; j < 64; j += 2) {
            ITER(j, 0)
            ITER(j + 1, 1)
        }
#undef ITER
#undef GSTAGE

        // epilogue: D row = (lane>>4)*4 + i, col = ct*16 + (lane&15)
#pragma unroll
        for (int ct = 0; ct < 4; ++ct) {
            int col = ct * 16 + l16;
            if (col >= HID) continue;
            float bias = b1[col];
#pragma unroll
            for (int rt = 0; rt < 2; ++rt)
#pragma unroll
                for (int i = 0; i < 4; ++i) {
                    long row = rowb + rt * 16 + lq * 4 + i;
                    if (row < nrows) {
                        float v = acc[rt][ct][i] + bias;
                        H[row * HID + col] = v > 0.f ? v : 0.f;
                    }
                }
        }
    } else {
        // ------------- scatter-bucket tile (4096 edges, rank-only regs) ----
        const int bid = blockIdx.x - ngemm;
        const int t = threadIdx.x;
        for (int i = t; i < 1024; i += 256) u.sc.hist[i] = 0;
        __syncthreads();

        const int e0 = bid * 4096;
        unsigned prA[16], prB[16];
#pragma unroll
        for (int k = 0; k < 16; ++k) {
            int e = e0 + k * 256 + t;
            if (e < m) {
                int x = sx[e], y = sy[e];
                int bA = x >> 7;
                prA[k] = ((unsigned)bA << 22) | (unsigned)atomicAdd(&u.sc.hist[bA], 1);
                int bB = y >> 7;
                prB[k] = ((unsigned)bB << 22) | (unsigned)atomicAdd(&u.sc.hist[bB], 1);
            } else {
                prA[k] = 0xFFFFFFFFu; prB[k] = 0xFFFFFFFFu;
            }
        }
        __syncthreads();
        for (int b = t; b < nbuck; b += 256) {
            int h = u.sc.hist[b];
            u.sc.gb[b] = h ? atomicAdd(&cursor[b * CSTRIDE], h) : 0;
        }
        __syncthreads();
#pragma unroll
        for (int k = 0; k < 16; ++k) {
            if (prA[k] == 0xFFFFFFFFu) continue;
            int e = e0 + k * 256 + t;
            int x = sx[e], y = sy[e];               // L2-hot re-read
            unsigned rb = __float_as_uint(rel[e]);
            {
                unsigned buck = prA[k] >> 22, rank = prA[k] & 0x3FFFFFu;
                unsigned slot = (unsigned)u.sc.gb[buck] + rank;
                if (slot < BCAP)
                    pool[(size_t)buck * BCAP + slot] =
                        make_uint2((unsigned)(x & 127) | ((unsigned)y << 8), rb);
            }
            {
                unsigned buck = prB[k] >> 22, rank = prB[k] & 0x3FFFFFu;
                unsigned slot = (unsigned)u.sc.gb[buck] + rank;
                if (slot < BCAP)
                    pool[(size_t)buck * BCAP + slot] =
                        make_uint2((unsigned)(y & 127) | 0x80u | ((unsigned)x << 8), rb);
            }
        }
    }
}

// exclusive scan of clamped bucket counts (nb <= 1024)
__global__ __launch_bounds__(1024) void scan_buckets(
    const int* __restrict__ cursor, int* __restrict__ bucket_base, int nb)
{
    __shared__ int s[1024];
    int t = threadIdx.x;
    int v = 0;
    if (t < nb) { v = cursor[t * CSTRIDE]; if (v > BCAP) v = BCAP; }
    s[t] = v;
    __syncthreads();
    for (int st = 1; st < 1024; st <<= 1) {
        int tmp = (t >= st) ? s[t - st] : 0;
        __syncthreads();
        s[t] += tmp;
        __syncthreads();
    }
    if (t < nb) bucket_base[t] = s[t] - v;
}

// ============ MEGA2: mlp blocks [0,nmlp) + sort blocks [nmlp,..) ============
__global__ __launch_bounds__(256) void mega2(
    const float* __restrict__ H,
    const float* __restrict__ W2, const float* __restrict__ b2,
    const float* __restrict__ W3, const float* __restrict__ b3,
    const float* __restrict__ Wl, const float* __restrict__ bl,
    float* __restrict__ Z, int n, int nmlp, int zs,
    const uint2* __restrict__ pool, const int* __restrict__ cursor,
    const int* __restrict__ bucket_base, uint2* __restrict__ recs,
    int* __restrict__ offs, int* __restrict__ deg)
{
    __shared__ union {
        struct {
            float w2[HID][52];
            float w3[HID][52];
            float wl[52][8];
            float bb2[52], bb3[52], bbl[8];
        } mlp;
        struct {
            int hist[128], nbase[128], cur[128], sc[128];
            ushort ord[BCAP];
        } srt;
    } u;

    if ((int)blockIdx.x < nmlp) {
        // ---------------- MLP tail ----------------
        for (int i = threadIdx.x; i < HID * 52; i += 256) {
            int r = i / 52, c = i % 52;
            u.mlp.w2[r][c] = (c < HID) ? W2[r * HID + c] : 0.f;
            u.mlp.w3[r][c] = (c < HID) ? W3[r * HID + c] : 0.f;
        }
        for (int i = threadIdx.x; i < 52 * 8; i += 256) {
            int r = i / 8, c = i % 8;
            u.mlp.wl[r][c] = (r < HID && c < NC) ? Wl[r * NC + c] : 0.f;
        }
        if (threadIdx.x < 52) {
            u.mlp.bb2[threadIdx.x] = (threadIdx.x < HID) ? b2[threadIdx.x] : 0.f;
            u.mlp.bb3[threadIdx.x] = (threadIdx.x < HID) ? b3[threadIdx.x] : 0.f;
        }
        if (threadIdx.x < 8) u.mlp.bbl[threadIdx.x] = (threadIdx.x < NC) ? bl[threadIdx.x] : 0.f;
        __syncthreads();

        long row = (long)blockIdx.x * 256 + threadIdx.x;
        if (row >= n) return;

        float x1[HID];
#pragma unroll
        for (int i = 0; i < HID / 2; ++i) {
            float2 t = *(const float2*)(H + row * HID + 2 * i);
            x1[2 * i] = t.x; x1[2 * i + 1] = t.y;
        }

        float x2[52];
#pragma unroll
        for (int j = 0; j < 52; ++j) x2[j] = u.mlp.bb2[j];
        for (int i = 0; i < HID; ++i) {
            float xi = x1[i];
#pragma unroll
            for (int jq = 0; jq < 13; ++jq) {
                float4 t = *(const float4*)&u.mlp.w2[i][jq * 4];
                x2[jq * 4 + 0] = fmaf(xi, t.x, x2[jq * 4 + 0]);
                x2[jq * 4 + 1] = fmaf(xi, t.y, x2[jq * 4 + 1]);
                x2[jq * 4 + 2] = fmaf(xi, t.z, x2[jq * 4 + 2]);
                x2[jq * 4 + 3] = fmaf(xi, t.w, x2[jq * 4 + 3]);
            }
        }
#pragma unroll
        for (int j = 0; j < 52; ++j) x2[j] = fmaxf(x2[j], 0.f);

        float z[NC];
#pragma unroll
        for (int c = 0; c < NC; ++c) z[c] = u.mlp.bbl[c];
        for (int jq = 0; jq < 13; ++jq) {
            float t0 = u.mlp.bb3[jq * 4 + 0], t1 = u.mlp.bb3[jq * 4 + 1];
            float t2 = u.mlp.bb3[jq * 4 + 2], t3 = u.mlp.bb3[jq * 4 + 3];
            for (int k = 0; k < HID; ++k) {
                float xk = x2[k];
                float4 wv = *(const float4*)&u.mlp.w3[k][jq * 4];
                t0 = fmaf(xk, wv.x, t0);
                t1 = fmaf(xk, wv.y, t1);
                t2 = fmaf(xk, wv.z, t2);
                t3 = fmaf(xk, wv.w, t3);
            }
            t0 = fmaxf(t0, 0.f); t1 = fmaxf(t1, 0.f);
            t2 = fmaxf(t2, 0.f); t3 = fmaxf(t3, 0.f);
#pragma unroll
            for (int c = 0; c < NC; ++c) {
                z[c] = fmaf(t0, u.mlp.wl[jq * 4 + 0][c], z[c]);
                z[c] = fmaf(t1, u.mlp.wl[jq * 4 + 1][c], z[c]);
                z[c] = fmaf(t2, u.mlp.wl[jq * 4 + 2][c], z[c]);
                z[c] = fmaf(t3, u.mlp.wl[jq * 4 + 3][c], z[c]);
            }
        }
        if (zs == ZS) {
            float* po = Z + (size_t)ZS * row;
            *(float4*)po       = make_float4(z[0], z[1], z[2], z[3]);
            *(float4*)(po + 4) = make_float4(z[4], z[5], 0.f, 0.f);
        } else {
#pragma unroll
            for (int c = 0; c < NC; ++c) Z[row * NC + c] = z[c];
        }
    } else {
        // ---------------- per-bucket counting sort ----------------
        const int b = blockIdx.x - nmlp;
        const int t = threadIdx.x;
        int cnt = cursor[b * CSTRIDE]; if (cnt > BCAP) cnt = BCAP;
        const int base = bucket_base[b];
        if (t < 128) u.srt.hist[t] = 0;
        __syncthreads();
        const uint2* bp = pool + (size_t)b * BCAP;
        for (int i = t; i < cnt; i += 256)
            atomicAdd(&u.srt.hist[bp[i].x & 127u], 1);
        __syncthreads();
        int v = (t < 128) ? u.srt.hist[t] : 0;
        if (t < 128) u.srt.sc[t] = v;
        __syncthreads();
        for (int st = 1; st < 128; st <<= 1) {
            int tmp = (t >= st && t < 128) ? u.srt.sc[t - st] : 0;
            __syncthreads();
            if (t < 128) u.srt.sc[t] += tmp;
            __syncthreads();
        }
        if (t < 128) {
            u.srt.nbase[t] = u.srt.sc[t] - v;
            u.srt.cur[t] = 0;
            int gnode = b * 128 + t;
            if (gnode < n) { offs[gnode] = base + u.srt.sc[t] - v; deg[gnode] = v; }
        }
        __syncthreads();
        for (int i = t; i < cnt; i += 256) {
            unsigned nl = bp[i].x & 127u;
            int rk = atomicAdd(&u.srt.cur[nl], 1);
            u.srt.ord[u.srt.nbase[nl] + rk] = (ushort)i;
        }
        __syncthreads();
        for (int i = t; i < cnt; i += 256) {
            uint2 r = bp[u.srt.ord[i]];
            unsigned side = (r.x >> 7) & 1u;
            unsigned other = r.x >> 8;
            recs[base + i] = make_uint2(other | (side << 31), r.y);
        }
    }
}

// ============ KENN layer: 8 lanes per node, shfl reduce, padded Z ============
__global__ __launch_bounds__(256) void kenn_gather8(
    const float* __restrict__ Zin, float* __restrict__ Zout,
    const int* __restrict__ offs, const int* __restrict__ deg,
    const uint2* __restrict__ recs, const float* __restrict__ cw,
    int n, int dofinal)
{
    int gt = blockIdx.x * 256 + threadIdx.x;
    int node = gt >> 3;
    int l8 = gt & 7;
    if (node >= n) return;

    float4 za = *(const float4*)(Zin + (size_t)ZS * node);
    float4 zb = *(const float4*)(Zin + (size_t)ZS * node + 4);
    float zown[NC] = { za.x, za.y, za.z, za.w, zb.x, zb.y };
    float acc[NC], cwv[NC];
#pragma unroll
    for (int c = 0; c < NC; ++c) { acc[c] = 0.f; cwv[c] = cw[c]; }

    const int start = offs[node];
    const int cnt = deg[node];

#pragma unroll 2
    for (int i = l8; i < cnt; i += 8) {
        uint2 rc = recs[start + i];
        const int other = (int)(rc.x & 0x7FFFFFFFu);
        const bool sideY = (rc.x & 0x80000000u) != 0;
        const float l0 = -__uint_as_float(rc.y);

        float4 oa = *(const float4*)(Zin + (size_t)ZS * other);
        float4 ob = *(const float4*)(Zin + (size_t)ZS * other + 4);
        float zo[NC] = { oa.x, oa.y, oa.z, oa.w, ob.x, ob.y };

#pragma unroll
        for (int c = 0; c < NC; ++c) {
            float zx = sideY ? zo[c] : zown[c];
            float zy = sideY ? zown[c] : zo[c];
            float l1 = -zx;
            float l2 = zy;
            float mx = fmaxf(l0, fmaxf(l1, l2));
            float e0 = __expf(l0 - mx);
            float e1 = __expf(l1 - mx);
            float e2 = __expf(l2 - mx);
            float g = cwv[c] * __builtin_amdgcn_rcpf(e0 + e1 + e2);
            acc[c] += sideY ? (e2 * g) : (-e1 * g);
        }
    }

#pragma unroll
    for (int c = 0; c < NC; ++c) {
        acc[c] += __shfl_xor(acc[c], 1, 64);
        acc[c] += __shfl_xor(acc[c], 2, 64);
        acc[c] += __shfl_xor(acc[c], 4, 64);
    }

    if (l8 != 0) return;

#pragma unroll
    for (int c = 0; c < NC; ++c) acc[c] += zown[c];

    if (dofinal) {
        float mx = acc[0];
#pragma unroll
        for (int c = 1; c < NC; ++c) mx = fmaxf(mx, acc[c]);
        float e[NC], s = 0.f;
#pragma unroll
        for (int c = 0; c < NC; ++c) { e[c] = __expf(acc[c] - mx); s += e[c]; }
        float inv = 1.f / s;
        float2* po = (float2*)(Zout + 6L * node);   // compact output
#pragma unroll
        for (int q = 0; q < 3; ++q) {
            float2 t; t.x = e[2 * q] * inv; t.y = e[2 * q + 1] * inv;
            po[q] = t;
        }
    } else {
        float* po = Zout + (size_t)ZS * node;
        *(float4*)po       = make_float4(acc[0], acc[1], acc[2], acc[3]);
        *(float4*)(po + 4) = make_float4(acc[4], acc[5], 0.f, 0.f);
    }
}

// ---------------- fallback path kernels (atomic version, compact Z) --------
__global__ __launch_bounds__(256) void kenn_edge(
    const float* __restrict__ Zold, float* __restrict__ Znew,
    const float* __restrict__ rel, const int* __restrict__ sx,
    const int* __restrict__ sy, const float* __restrict__ cw, int m)
{
    int idx = blockIdx.x * 256 + threadIdx.x;
    if (idx >= m) return;
    const int x = sx[idx];
    const int y = sy[idx];
    const float l0 = -rel[idx];

    float zx[NC], zy[NC];
    const float2* px = (const float2*)(Zold + 6L * x);
    const float2* py = (const float2*)(Zold + 6L * y);
#pragma unroll
    for (int q = 0; q < 3; ++q) {
        float2 t = px[q]; zx[2 * q] = t.x; zx[2 * q + 1] = t.y;
        float2 u = py[q]; zy[2 * q] = u.x; zy[2 * q + 1] = u.y;
    }
#pragma unroll
    for (int c = 0; c < NC; ++c) {
        float l1 = -zx[c];
        float l2 = zy[c];
        float mx = fmaxf(l0, fmaxf(l1, l2));
        float e0 = __expf(l0 - mx);
        float e1 = __expf(l1 - mx);
        float e2 = __expf(l2 - mx);
        float s = cw[c] / (e0 + e1 + e2);
        atomicAdd(&Znew[6L * x + c], -e1 * s);
        atomicAdd(&Znew[6L * y + c],  e2 * s);
    }
}

__global__ __launch_bounds__(256) void softmax6(
    const float* __restrict__ Z, float* __restrict__ out, int n)
{
    long row = (long)blockIdx.x * 256 + threadIdx.x;
    if (row >= n) return;
    float v[NC];
    const float2* p = (const float2*)(Z + row * 6);
#pragma unroll
    for (int q = 0; q < 3; ++q) { float2 t = p[q]; v[2 * q] = t.x; v[2 * q + 1] = t.y; }
    float mx = v[0];
#pragma unroll
    for (int c = 1; c < NC; ++c) mx = fmaxf(mx, v[c]);
    float e[NC], s = 0.f;
#pragma unroll
    for (int c = 0; c < NC; ++c) { e[c] = __expf(v[c] - mx); s += e[c]; }
    float inv = 1.f / s;
    float2* po = (float2*)(out + row * 6);
#pragma unroll
    for (int q = 0; q < 3; ++q) {
        float2 t; t.x = e[2 * q] * inv; t.y = e[2 * q + 1] * inv;
        po[q] = t;
    }
}

extern "C" void kernel_launch(void* const* d_in, const int* in_sizes, int n_in,
                              void* d_out, int out_size, void* d_ws, size_t ws_size,
                              hipStream_t stream)
{
    const float* F   = (const float*)d_in[0];
    const float* rel = (const float*)d_in[1];
    const int*   sx  = (const int*)d_in[2];
    const int*   sy  = (const int*)d_in[3];
    const float* W1  = (const float*)d_in[4];
    const float* b1  = (const float*)d_in[5];
    const float* W2  = (const float*)d_in[6];
    const float* b2  = (const float*)d_in[7];
    const float* W3  = (const float*)d_in[8];
    const float* b3  = (const float*)d_in[9];
    const float* Wl  = (const float*)d_in[10];
    const float* bl  = (const float*)d_in[11];
    const float* cw1 = (const float*)d_in[12];
    const float* cw2 = (const float*)d_in[13];
    const float* cw3 = (const float*)d_in[14];

    const int n = in_sizes[0] / D_FEAT;   // 100000
    const int m = in_sizes[1];            // 3200000
    const int nbuck = (n + 127) >> 7;     // 782

    // workspace layout (all segments 8B-aligned)
    float*  H    = (float*)d_ws;                      // n*HID
    float*  Zp0  = H + (size_t)n * HID;               // n*ZS (also compact fallback)
    float*  Zp1  = Zp0 + (size_t)n * ZS;              // n*ZS
    ushort* Whi  = (ushort*)(Zp1 + (size_t)n * ZS);   // 262144
    ushort* Wlo  = Whi + 262144;                      // 262144
    int* deg     = (int*)(Wlo + 262144);              // n
    int* offs    = deg + n;                           // n
    int* bbase   = offs + n;                          // 1024
    int* cursor  = bbase + 1024;                      // 1024*CSTRIDE
    uint2* recs  = (uint2*)(cursor + 1024 * CSTRIDE); // 2m
    uint2* pool  = recs + 2 * (size_t)m;              // nbuck*BCAP

    const size_t need = ((char*)(pool + (size_t)nbuck * BCAP)) - (char*)d_ws;

    const int ngemm = (n + 127) / 128;          // 782
    const int nscat = (m + 4095) / 4096;        // 782
    const int nmlp  = (n + 255) / 256;          // 391
    const int g8blk = (8 * n + 255) / 256;
    const int eblk  = (m + 255) / 256;

    prep_wfrag<<<1024, 256, 0, stream>>>(W1, Whi, Wlo);

    if (ws_size >= need && nbuck <= 1024) {
        hipMemsetAsync(cursor, 0, (size_t)nbuck * CSTRIDE * sizeof(int), stream);
        // mega1: gemm ∪ scatter (overlapped on CUs)
        mega1<<<ngemm + nscat, 256, 0, stream>>>(
            F, Whi, Wlo, b1, H, n, ngemm,
            sx, sy, rel, cursor, pool, m, nbuck);
        scan_buckets<<<1, 1024, 0, stream>>>(cursor, bbase, nbuck);
        // mega2: mlp (padded Z out) ∪ sort (overlapped)
        mega2<<<nmlp + nbuck, 256, 0, stream>>>(
            H, W2, b2, W3, b3, Wl, bl, Zp0, n, nmlp, ZS,
            pool, cursor, bbase, recs, offs, deg);

        kenn_gather8<<<g8blk, 256, 0, stream>>>(Zp0, Zp1, offs, deg, recs, cw1, n, 0);
        kenn_gather8<<<g8blk, 256, 0, stream>>>(Zp1, Zp0, offs, deg, recs, cw2, n, 0);
        kenn_gather8<<<g8blk, 256, 0, stream>>>(Zp0, (float*)d_out, offs, deg, recs, cw3, n, 1);
    } else {
        // fallback: compact Z path with atomic kenn_edge
        mega1<<<ngemm, 256, 0, stream>>>(
            F, Whi, Wlo, b1, H, n, ngemm,
            sx, sy, rel, (int*)nullptr, (uint2*)nullptr, m, nbuck);
        mega2<<<nmlp, 256, 0, stream>>>(
            H, W2, b2, W3, b3, Wl, bl, Zp0, n, nmlp, NC,
            (const uint2*)nullptr, (const int*)nullptr, (const int*)nullptr,
            (uint2*)nullptr, (int*)nullptr, (int*)nullptr);

        const size_t zbytes = (size_t)n * NC * sizeof(float);
        hipMemcpyAsync(Zp1, Zp0, zbytes, hipMemcpyDeviceToDevice, stream);
        kenn_edge<<<eblk, 256, 0, stream>>>(Zp0, Zp1, rel, sx, sy, cw1, m);
        hipMemcpyAsync(Zp0, Zp1, zbytes, hipMemcpyDeviceToDevice, stream);
        kenn_edge<<<eblk, 256, 0, stream>>>(Zp1, Zp0, rel, sx, sy, cw2, m);
        hipMemcpyAsync(Zp1, Zp0, zbytes, hipMemcpyDeviceToDevice, stream);
        kenn_edge<<<eblk, 256, 0, stream>>>(Zp0, Zp1, rel, sx, sy, cw3, m);
        softmax6<<<nmlp, 256, 0, stream>>>(Zp1, (float*)d_out, n);
    }
}